// Round 1
// 349.395 us; speedup vs baseline: 1.0430x; 1.0430x over previous
//
#include <hip/hip_runtime.h>

// Problem constants
#define B_  16
#define S_  1024
#define IN_ 1024
#define H_  1024
#define N1  (2*H_)          // 2048 output cols of GEMM1
#define M1  (B_*S_)         // 16384 rows of GEMM1
#define K1  IN_             // 1024
#define XN  (M1*IN_)        // 16,777,216 elems of x
#define WN  (N1*IN_)        //  2,097,152 elems of W
#define LDG 1024            // k-extent (row stride) of every GEMM operand here

// 256x256x64 8-wave pipelined tile (8-phase-class schedule)
#define BM  256
#define BN  256
#define BK  64              // row = 128 B = 8 chunks of 16 B (XOR-8 swizzled)
#define CP  257             // epilogue transpose LDS stride (odd -> conflict-free)

typedef __attribute__((ext_vector_type(8))) short  short8;   // 8 bf16 (MFMA A/B frag)
typedef __attribute__((ext_vector_type(4))) float  floatx4;  // MFMA C/D frag

// fp32 -> bf16 round-to-nearest-even
__device__ __forceinline__ unsigned short f2bf(float f) {
    unsigned int u = __float_as_uint(f);
    u += 0x7fffu + ((u >> 16) & 1u);
    return (unsigned short)(u >> 16);
}

// async global->LDS, 16 B per lane; LDS dst is wave-uniform base + lane*16
#define GLDS16(gp, lp) __builtin_amdgcn_global_load_lds(                      \
    (const __attribute__((address_space(1))) void*)(gp),                      \
    (__attribute__((address_space(3))) void*)(lp), 16, 0, 0)

// ---------------------------------------------------------------------------
// convert: fp32 -> bf16 for x and W (memory-bound). Unchanged.
// ---------------------------------------------------------------------------
__global__ __launch_bounds__(256) void convert_kernel(
    const float* __restrict__ x, const float* __restrict__ W,
    unsigned short* __restrict__ xb, unsigned short* __restrict__ Wb)
{
    size_t i = ((size_t)blockIdx.x * 256 + threadIdx.x) * 8;
    const float* src;
    unsigned short* dst;
    if (i < (size_t)XN) { src = x + i; dst = xb + i; }
    else                { src = W + (i - XN); dst = Wb + (i - XN); }
    float4 a = *(const float4*)(src);
    float4 b = *(const float4*)(src + 4);
    ushort4 p = { f2bf(a.x), f2bf(a.y), f2bf(a.z), f2bf(a.w) };
    ushort4 q = { f2bf(b.x), f2bf(b.y), f2bf(b.z), f2bf(b.w) };
    *(ushort4*)(dst)     = p;
    *(ushort4*)(dst + 4) = q;
}

// ---------------------------------------------------------------------------
// stage one 16 KiB quarter of the NEXT K-tile into an LDS buffer.
// u: 0,1 = A row-halves [0,128)/[128,256); 2,3 = B row-halves.
// XOR-8 chunk swizzle applied on the GLOBAL source (pre-swizzled source +
// linear LDS dest: global_load_lds writes base+lane*16 only). 2 loads/thread.
// ---------------------------------------------------------------------------
__device__ __forceinline__ void stage_unit(
    const unsigned short* Ag, const unsigned short* Bg,
    unsigned short* lbuf, int u, int kt, int wave, int lane)
{
    const unsigned short* src = (u < 2) ? (Ag + (size_t)u * 128 * LDG)
                                        : (Bg + (size_t)(u - 2) * 128 * LDG);
    unsigned short* dstu = lbuf + ((u < 2) ? u * 8192 : 16384 + (u - 2) * 8192);
#pragma unroll
    for (int h = 0; h < 2; ++h) {
        int e   = (wave * 2 + h) * 64 + lane;   // chunk id 0..1023 within unit
        int row = e >> 3, c = e & 7;
        int cs  = c ^ (row & 7);                // source swizzle; read side XORs same
        GLDS16(src + (size_t)row * LDG + kt + cs * 8, dstu + (wave * 2 + h) * 512);
    }
}

// ---------------------------------------------------------------------------
// K-loop core: 16 K-tiles of 64, double-buffered (2 x 64 KiB), 4 phases per
// tile: {ds_read A-subtile (+B on kc-entry) | stage 1 quarter of tile t+1 |
// s_barrier | setprio(1) 16 MFMA setprio(0) | s_barrier}.
// Only correctness-critical sync: loop-top __syncthreads (its vmcnt(0) covers
// loads issued 1-4 phases earlier -> cheap). Wave tile 128x64, acc[8][4].
// ---------------------------------------------------------------------------
__device__ __forceinline__ void gemm_core(
    const unsigned short* Ag, const unsigned short* Bg,
    unsigned short* lds, floatx4 (&acc)[8][4], int wave, int lane)
{
    const int quad = lane >> 4, r = lane & 15;
    const int wmw  = (wave >> 2) * 128;          // 2 wave rows x 4 wave cols
    const int wnw  = (wave & 3) * 64;

#pragma unroll
    for (int u = 0; u < 4; ++u) stage_unit(Ag, Bg, lds, u, 0, wave, lane);

    for (int t = 0; t < 16; ++t) {
        unsigned short* bufc = lds + (t & 1) * 32768;
        unsigned short* bufn = lds + ((t + 1) & 1) * 32768;
        const int  ktn = (t + 1) * BK;
        const bool st  = (t < 15);
        __syncthreads();                          // tile t's staged loads landed
        const unsigned short* cA = bufc;
        const unsigned short* cB = bufc + 16384;
        short8 bfr[4];
#pragma unroll
        for (int kc = 0; kc < 2; ++kc)
#pragma unroll
        for (int mh = 0; mh < 2; ++mh) {
            const int g = kc * 4 + quad;          // k-chunk index in [0,8)
            short8 af[4];
#pragma unroll
            for (int i = 0; i < 4; ++i)
                af[i] = *(const short8*)(cA + (wmw + (mh * 4 + i) * 16 + r) * BK
                                            + (g ^ (r & 7)) * 8);
            if (mh == 0) {                        // B frags shared across mh phases
#pragma unroll
                for (int j = 0; j < 4; ++j)
                    bfr[j] = *(const short8*)(cB + (wnw + j * 16 + r) * BK
                                                 + (g ^ (r & 7)) * 8);
            }
            if (st) stage_unit(Ag, Bg, bufn, kc * 2 + mh, ktn, wave, lane);
            __builtin_amdgcn_sched_barrier(0);    // keep issue group above barrier
            __builtin_amdgcn_s_barrier();
            __builtin_amdgcn_s_setprio(1);
#pragma unroll
            for (int i = 0; i < 4; ++i)
#pragma unroll
                for (int j = 0; j < 4; ++j)
                    acc[mh * 4 + i][j] = __builtin_amdgcn_mfma_f32_16x16x32_bf16(
                        af[i], bfr[j], acc[mh * 4 + i][j], 0, 0, 0);
            __builtin_amdgcn_s_setprio(0);
            __builtin_amdgcn_sched_barrier(0);    // keep MFMA cluster intact
            if (kc + mh < 2) __builtin_amdgcn_s_barrier();  // last one merges into
        }                                                   // next loop-top sync
    }
    __syncthreads();                              // LDS reusable by epilogue
}

// ---------------------------------------------------------------------------
// GEMM1: C[m,n] = sum_k xb[m,k]*Wb[n,k]; relu -> fp32 keys/vals to d_out and
// bf16 transposed keysT/valsT to ws. 512 blocks; XCD x owns m-stripe
// [8x,8x+8) x all 8 n-tiles (A panels L2-shared; whole W = 4 MB, L3-resident).
// ---------------------------------------------------------------------------
__global__ __launch_bounds__(512, 2) void gemm1_kernel(
    const unsigned short* __restrict__ xb, const unsigned short* __restrict__ Wb,
    float* __restrict__ out,
    unsigned short* __restrict__ kT, unsigned short* __restrict__ vT)
{
    __shared__ unsigned short lds[65536];         // 128 KiB

    const int tid  = threadIdx.x;
    const int wave = tid >> 6, lane = tid & 63;
    const int quad = lane >> 4, r = lane & 15;
    const int wmw  = (wave >> 2) * 128;
    const int wnw  = (wave & 3) * 64;

    const int L   = blockIdx.x;
    const int xcd = L & 7, s = L >> 3;            // s: 0..63
    const int mt  = xcd * 8 + (s >> 3);           // 0..63
    const int nt  = s & 7;                        // 0..7
    const int m0  = mt * BM, n0 = nt * BN;

    const unsigned short* Ag = xb + (size_t)m0 * K1;
    const unsigned short* Bg = Wb + (size_t)n0 * K1;

    floatx4 acc[8][4] = {};
    gemm_core(Ag, Bg, lds, acc, wave, lane);

    const bool isKeys = (nt < 4);
    float* outKV    = out + (isKeys ? (size_t)M1 * H_ : (size_t)2 * M1 * H_);
    const int ncol0 = isKeys ? n0 : (n0 - 1024);

    // fp32 relu writes (each wave its own 128x64 region)
#pragma unroll
    for (int f = 0; f < 8; ++f)
#pragma unroll
        for (int j = 0; j < 4; ++j)
#pragma unroll
            for (int d = 0; d < 4; ++d) {
                int row_l = wmw + f * 16 + quad * 4 + d;
                int col_l = wnw + j * 16 + r;
                outKV[(size_t)(m0 + row_l) * H_ + ncol0 + col_l] =
                    fmaxf(acc[f][j][d], 0.0f);
            }

    // bf16 transposed writes via LDS, 2 chunks of 128 rows (CP=257 -> no
    // bank conflicts on either side; stores 8 B/lane coalesced)
    unsigned short* wsT = isKeys ? kT : vT;
    const int b  = m0 >> 10;
    const int s0 = m0 & 1023;
    unsigned short* dstB = wsT + (size_t)b * H_ * S_ + (size_t)ncol0 * S_ + s0;

#pragma unroll
    for (int ch = 0; ch < 2; ++ch) {
        if ((wave >> 2) == ch) {
#pragma unroll
            for (int f = 0; f < 8; ++f)
#pragma unroll
                for (int j = 0; j < 4; ++j)
#pragma unroll
                    for (int d = 0; d < 4; ++d) {
                        int lrow = f * 16 + quad * 4 + d;    // 0..127
                        int col  = wnw + j * 16 + r;         // 0..255
                        lds[lrow * CP + col] = f2bf(fmaxf(acc[f][j][d], 0.0f));
                    }
        }
        __syncthreads();
#pragma unroll
        for (int it = 0; it < 16; ++it) {
            int o   = it * 512 + tid;
            int n_l = o >> 5;                     // 0..255
            int m4  = (o & 31) * 4;               // 0..124
            ushort4 v;
            v.x = lds[(m4 + 0) * CP + n_l];
            v.y = lds[(m4 + 1) * CP + n_l];
            v.z = lds[(m4 + 2) * CP + n_l];
            v.w = lds[(m4 + 3) * CP + n_l];
            *(ushort4*)(dstB + (size_t)n_l * S_ + ch * 128 + m4) = v;
        }
        __syncthreads();
    }
}

// ---------------------------------------------------------------------------
// GEMM2 (batched): mem[b][m,n] = sum_t keysT[b][m,t]*valsT[b][n,t].
// 256 blocks; XCD x owns batches {2x,2x+1} (4 MB working set fits its L2).
// ---------------------------------------------------------------------------
__global__ __launch_bounds__(512, 2) void gemm2_kernel(
    const unsigned short* __restrict__ kT, const unsigned short* __restrict__ vT,
    float* __restrict__ mem)
{
    __shared__ unsigned short lds[65536];         // 128 KiB

    const int tid  = threadIdx.x;
    const int wave = tid >> 6, lane = tid & 63;
    const int quad = lane >> 4, r = lane & 15;
    const int wmw  = (wave >> 2) * 128;
    const int wnw  = (wave & 3) * 64;

    const int L   = blockIdx.x;
    const int xcd = L & 7, s = L >> 3;            // s: 0..31
    const int b   = xcd * 2 + (s >> 4);           // batch
    const int tt  = s & 15;
    const int m0  = (tt >> 2) * BM;
    const int n0  = (tt & 3) * BN;

    const unsigned short* Ag = kT + (size_t)b * H_ * S_ + (size_t)m0 * S_;
    const unsigned short* Bg = vT + (size_t)b * H_ * S_ + (size_t)n0 * S_;

    floatx4 acc[8][4] = {};
    gemm_core(Ag, Bg, lds, acc, wave, lane);

    float* outb = mem + (size_t)b * H_ * H_;
#pragma unroll
    for (int f = 0; f < 8; ++f)
#pragma unroll
        for (int j = 0; j < 4; ++j)
#pragma unroll
            for (int d = 0; d < 4; ++d) {
                int row_l = wmw + f * 16 + quad * 4 + d;
                int col_l = wnw + j * 16 + r;
                outb[(size_t)(m0 + row_l) * H_ + n0 + col_l] = acc[f][j][d];
            }
}

extern "C" void kernel_launch(void* const* d_in, const int* in_sizes, int n_in,
                              void* d_out, int out_size, void* d_ws, size_t ws_size,
                              hipStream_t stream) {
    const float* x = (const float*)d_in[0];   // [16,1024,1024] f32
    const float* W = (const float*)d_in[1];   // [2048,1024] f32
    float* out = (float*)d_out;               // mem(16M) | keys(16M) | vals(16M) f32

    // Stash bf16 inputs in d_out's mem region (not written until gemm2)
    unsigned short* xb = (unsigned short*)d_out;            // 33.5 MB
    unsigned short* Wb = xb + (size_t)XN;                   //  4.2 MB (total 37.7 < 64 MB)

    // ws: keysT/valsT bf16 [B][H][S] (64 MB)
    unsigned short* kT = (unsigned short*)d_ws;
    unsigned short* vT = kT + (size_t)B_ * H_ * S_;

    convert_kernel<<<dim3((XN + WN) / 2048), dim3(256), 0, stream>>>(x, W, xb, Wb);

    gemm1_kernel<<<dim3(512), dim3(512), 0, stream>>>(xb, Wb, out, kT, vT);

    gemm2_kernel<<<dim3(256), dim3(512), 0, stream>>>(kT, vT, out);
}